// Round 10
// baseline (4877.145 us; speedup 1.0000x reference)
//
#include <hip/hip_runtime.h>

#define DEV __device__ __forceinline__

using u16 = unsigned short;
typedef __attribute__((ext_vector_type(8))) short          bf16x8;
typedef __attribute__((ext_vector_type(8))) unsigned short u16x8;
typedef __attribute__((ext_vector_type(4))) unsigned short u16x4;
typedef __attribute__((ext_vector_type(4))) float          f32x4;

// Problem constants
constexpr int NB = 8, SEQ = 1024, DM = 1024, NHEAD = 16, NLAYER = 8, NVOCAB = 8192;
constexpr int HD = 64;                 // head dim
constexpr int ROWS = NB * SEQ;         // 8192 token rows

// ---------- helpers ----------
DEV u16 f2b(float f) {                 // f32 -> bf16 RNE
  unsigned u = __float_as_uint(f);
  u += 0x7fffu + ((u >> 16) & 1u);
  return (u16)(u >> 16);
}

DEV void gload_lds16(const void* g, void* l) {
  // async global->LDS, 16B/lane. LDS dest is wave-uniform base + lane*16 (m104);
  // our per-lane pointers follow exactly that pattern.
  using GP = const __attribute__((address_space(1))) void*;
  using LP = __attribute__((address_space(3))) void*;
  __builtin_amdgcn_global_load_lds((GP)g, (LP)l, 16, 0, 0);
}

DEV f32x4 mfma16(bf16x8 a, bf16x8 b, f32x4 c) {
  return __builtin_amdgcn_mfma_f32_16x16x32_bf16(a, b, c, 0, 0, 0);
}

// ---------- f32 -> bf16 convert ----------
__global__ void k_cvt(const float* __restrict__ in, u16* __restrict__ out, int n4) {
  int i = blockIdx.x * 256 + threadIdx.x;
  if (i >= n4) return;
  float4 f = reinterpret_cast<const float4*>(in)[i];
  u16x4 o = { f2b(f.x), f2b(f.y), f2b(f.z), f2b(f.w) };
  reinterpret_cast<u16x4*>(out)[i] = o;
}

// ---------- embedding: tok + global_pos[timestep] + pos ----------
__global__ void k_embed(const int* __restrict__ idx, const int* __restrict__ ts,
                        const float* __restrict__ tok, const float* __restrict__ gpe,
                        const float* __restrict__ pe, float* __restrict__ x) {
  int row = blockIdx.x;                 // b*SEQ + t
  int b = row >> 10, t = row & 1023;
  int i = threadIdx.x;                  // 256 float4 per row
  const float4* a = reinterpret_cast<const float4*>(tok + (size_t)idx[row] * DM);
  const float4* g = reinterpret_cast<const float4*>(gpe + (size_t)ts[b] * DM);
  const float4* p = reinterpret_cast<const float4*>(pe + (size_t)t * DM);
  float4 va = a[i], vg = g[i], vp = p[i];
  reinterpret_cast<float4*>(x + (size_t)row * DM)[i] =
      make_float4(va.x + vg.x + vp.x, va.y + vg.y + vp.y,
                  va.z + vg.z + vp.z, va.w + vg.w + vp.w);
}

// ---------- LayerNorm (f32 in, bf16 out), one wave per row ----------
__global__ __launch_bounds__(256) void k_ln(const float* __restrict__ x,
                                            const float* __restrict__ w,
                                            const float* __restrict__ b,
                                            u16* __restrict__ out) {
  int row  = blockIdx.x * 4 + (threadIdx.x >> 6);
  int lane = threadIdx.x & 63;
  const float4* xr = reinterpret_cast<const float4*>(x + (size_t)row * DM);
  float4 v[4];
  float s = 0.f;
#pragma unroll
  for (int i = 0; i < 4; ++i) {
    v[i] = xr[lane + 64 * i];
    s += v[i].x + v[i].y + v[i].z + v[i].w;
  }
#pragma unroll
  for (int o = 1; o < 64; o <<= 1) s += __shfl_xor(s, o);
  float mean = s * (1.f / DM);
  float ss = 0.f;
#pragma unroll
  for (int i = 0; i < 4; ++i) {
    float dx = v[i].x - mean, dy = v[i].y - mean, dz = v[i].z - mean, dw = v[i].w - mean;
    ss += dx * dx + dy * dy + dz * dz + dw * dw;
  }
#pragma unroll
  for (int o = 1; o < 64; o <<= 1) ss += __shfl_xor(ss, o);
  float inv = rsqrtf(ss * (1.f / DM) + 1e-5f);
  const float4* wr = reinterpret_cast<const float4*>(w);
  const float4* br = reinterpret_cast<const float4*>(b);
  u16x4* orow = reinterpret_cast<u16x4*>(out + (size_t)row * DM);
#pragma unroll
  for (int i = 0; i < 4; ++i) {
    int c = lane + 64 * i;
    float4 wv = wr[c], bv = br[c];
    u16x4 o4 = { f2b((v[i].x - mean) * inv * wv.x + bv.x),
                 f2b((v[i].y - mean) * inv * wv.y + bv.y),
                 f2b((v[i].z - mean) * inv * wv.z + bv.z),
                 f2b((v[i].w - mean) * inv * wv.w + bv.w) };
    orow[c] = o4;
  }
}

// ---------- GEMM: C[M,N] = A[M,K] @ Bt[N,K]^T (+bias) , m97 structure ----------
// EPI: 0 = bf16 out, 1 = gelu->bf16 out, 2 = f32 out = res + acc + bias, 3 = f32 out
template <int EPI>
__global__ __launch_bounds__(256) void k_gemm(const u16* __restrict__ A,
                                              const u16* __restrict__ Bt,
                                              const float* __restrict__ bias,
                                              const float* __restrict__ res,
                                              void* __restrict__ outp,
                                              int M, int N, int K) {
  __shared__ __align__(16) u16 lA[128 * 32];
  __shared__ __align__(16) u16 lB[128 * 32];
  const int tid = threadIdx.x;
  const int wave = tid >> 6, lane = tid & 63, lg = lane >> 4, lr = lane & 15;
  const int wr = wave >> 1, wc = wave & 1;   // 2x2 wave grid, 64x64 per wave
  const size_t brow = (size_t)blockIdx.x * 128, bcol = (size_t)blockIdx.y * 128;
  f32x4 acc[4][4] = {};
  const int c2 = tid + 256;
  const size_t ar0 = (brow + (tid >> 2)) * (size_t)K + (tid & 3) * 8;
  const size_t ar1 = (brow + (c2 >> 2)) * (size_t)K + (c2 & 3) * 8;
  const size_t br0 = (bcol + (tid >> 2)) * (size_t)K + (tid & 3) * 8;
  const size_t br1 = (bcol + (c2 >> 2)) * (size_t)K + (c2 & 3) * 8;

  for (int k0 = 0; k0 < K; k0 += 32) {
    __syncthreads();
    gload_lds16(A + ar0 + k0, &lA[tid * 8]);
    gload_lds16(A + ar1 + k0, &lA[c2 * 8]);
    gload_lds16(Bt + br0 + k0, &lB[tid * 8]);
    gload_lds16(Bt + br1 + k0, &lB[c2 * 8]);
    __syncthreads();
    bf16x8 af[4], bfr[4];
#pragma unroll
    for (int m = 0; m < 4; ++m)
      af[m] = *reinterpret_cast<const bf16x8*>(&lA[(wr * 64 + m * 16 + lr) * 32 + lg * 8]);
#pragma unroll
    for (int n = 0; n < 4; ++n)
      bfr[n] = *reinterpret_cast<const bf16x8*>(&lB[(wc * 64 + n * 16 + lr) * 32 + lg * 8]);
#pragma unroll
    for (int m = 0; m < 4; ++m)
#pragma unroll
      for (int n = 0; n < 4; ++n)
        acc[m][n] = mfma16(af[m], bfr[n], acc[m][n]);
  }

  float bn[4] = {0.f, 0.f, 0.f, 0.f};
  if (bias) {
#pragma unroll
    for (int n = 0; n < 4; ++n) bn[n] = bias[bcol + wc * 64 + n * 16 + lr];
  }
#pragma unroll
  for (int m = 0; m < 4; ++m) {
#pragma unroll
    for (int j = 0; j < 4; ++j) {
      size_t r  = brow + wr * 64 + m * 16 + lg * 4 + j;
      size_t rb = r * (size_t)N + bcol + wc * 64 + lr;
#pragma unroll
      for (int n = 0; n < 4; ++n) {
        float v = acc[m][n][j] + bn[n];
        size_t off = rb + n * 16;
        if constexpr (EPI == 0) {
          ((u16*)outp)[off] = f2b(v);
        } else if constexpr (EPI == 1) {
          float gg = 0.5f * v * (1.f + erff(v * 0.70710678118f));
          ((u16*)outp)[off] = f2b(gg);
        } else if constexpr (EPI == 2) {
          ((float*)outp)[off] = res[off] + v;
        } else {
          ((float*)outp)[off] = v;
        }
      }
    }
  }
}

// ---------- causal flash attention (bf16 in/out, f32 online softmax) ----------
// grid (SEQ/64, NHEAD, NB), 256 threads. Wave w owns q rows qb*64+w*16..+15.
__global__ __launch_bounds__(256) void k_attn(const u16* __restrict__ Q,
                                              const u16* __restrict__ K,
                                              const u16* __restrict__ V,
                                              u16* __restrict__ Y) {
  const int qb = blockIdx.x, h = blockIdx.y, b = blockIdx.z;
  const int tid = threadIdx.x;
  const int wave = tid >> 6, lane = tid & 63, lg = lane >> 4, lr = lane & 15;
  __shared__ __align__(16) u16 Ks[32 * 64];      // [key][d]
  __shared__ __align__(16) u16 Vt[64 * 40];      // [d][key], pad 40 (16B-aligned rows)
  __shared__ __align__(16) u16 Ps[4][16 * 32];   // per-wave P re-layout buffer
  const size_t base = ((size_t)b * SEQ) * DM + h * HD;
  const int qrow0 = qb * 64 + wave * 16;
  const u16* qp = Q + base + (size_t)(qrow0 + lr) * DM + lg * 8;
  bf16x8 qf0 = *reinterpret_cast<const bf16x8*>(qp);
  bf16x8 qf1 = *reinterpret_cast<const bf16x8*>(qp + 32);
  float mrow[4] = {-1e30f, -1e30f, -1e30f, -1e30f};
  float lsum[4] = {0.f, 0.f, 0.f, 0.f};
  f32x4 o[4] = {};
  const int key_s = tid >> 3, d_s = (tid & 7) * 8;   // staging assignment
  const int nkb = (qb + 1) * 2;                      // 32-key blocks needed

  for (int kb = 0; kb < nkb; ++kb) {
    __syncthreads();
    {
      const size_t src = base + (size_t)(kb * 32 + key_s) * DM + d_s;
      *reinterpret_cast<u16x8*>(&Ks[key_s * 64 + d_s]) =
          *reinterpret_cast<const u16x8*>(K + src);
      u16x8 vv = *reinterpret_cast<const u16x8*>(V + src);
#pragma unroll
      for (int i = 0; i < 8; ++i) Vt[(d_s + i) * 40 + key_s] = vv[i];
    }
    __syncthreads();
    if (kb * 32 <= qrow0 + 15) {                 // skip fully-masked blocks
      f32x4 s[2];
#pragma unroll
      for (int ks = 0; ks < 2; ++ks) {
        bf16x8 kf0 = *reinterpret_cast<const bf16x8*>(&Ks[(ks * 16 + lr) * 64 + lg * 8]);
        bf16x8 kf1 = *reinterpret_cast<const bf16x8*>(&Ks[(ks * 16 + lr) * 64 + 32 + lg * 8]);
        f32x4 z = {};
        z = mfma16(qf0, kf0, z);
        z = mfma16(qf1, kf1, z);
        s[ks] = z;
      }
      float p0[4], p1[4];
#pragma unroll
      for (int j = 0; j < 4; ++j) {
        const int rowg = qrow0 + lg * 4 + j;
        float s0 = s[0][j] * 0.125f;             // 1/sqrt(64)
        float s1 = s[1][j] * 0.125f;
        if (kb * 32 + lr > rowg)      s0 = -1e30f;
        if (kb * 32 + 16 + lr > rowg) s1 = -1e30f;
        float mx = fmaxf(s0, s1);
#pragma unroll
        for (int off = 1; off < 16; off <<= 1) mx = fmaxf(mx, __shfl_xor(mx, off));
        float nm = fmaxf(mrow[j], mx);
        s0 = __expf(s0 - nm);
        s1 = __expf(s1 - nm);
        float rs = s0 + s1;
#pragma unroll
        for (int off = 1; off < 16; off <<= 1) rs += __shfl_xor(rs, off);
        float sc = __expf(mrow[j] - nm);
        lsum[j] = lsum[j] * sc + rs;
        mrow[j] = nm;
#pragma unroll
        for (int n = 0; n < 4; ++n) o[n][j] *= sc;
        p0[j] = s0;
        p1[j] = s1;
      }
#pragma unroll
      for (int j = 0; j < 4; ++j) {              // P: C-layout -> LDS
        Ps[wave][(lg * 4 + j) * 32 + lr]      = f2b(p0[j]);
        Ps[wave][(lg * 4 + j) * 32 + 16 + lr] = f2b(p1[j]);
      }
      bf16x8 pa = *reinterpret_cast<const bf16x8*>(&Ps[wave][lr * 32 + lg * 8]);
#pragma unroll
      for (int n = 0; n < 4; ++n) {              // O += P @ V
        bf16x8 vb = *reinterpret_cast<const bf16x8*>(&Vt[(n * 16 + lr) * 40 + lg * 8]);
        o[n] = mfma16(pa, vb, o[n]);
      }
    }
  }
#pragma unroll
  for (int j = 0; j < 4; ++j) {
    float inv = 1.f / lsum[j];
    u16* yp = Y + base + (size_t)(qrow0 + lg * 4 + j) * DM;
#pragma unroll
    for (int n = 0; n < 4; ++n) yp[n * 16 + lr] = f2b(o[n][j] * inv);
  }
}

// ---------- orchestration ----------
extern "C" void kernel_launch(void* const* d_in, const int* in_sizes, int n_in,
                              void* d_out, int out_size, void* d_ws, size_t ws_size,
                              hipStream_t stream) {
  (void)in_sizes; (void)n_in; (void)out_size; (void)ws_size;
  const int*   idx  = (const int*)  d_in[0];
  const int*   ts   = (const int*)  d_in[1];
  const float* tok  = (const float*)d_in[2];
  const float* pe   = (const float*)d_in[3];
  const float* gpe  = (const float*)d_in[4];
  const float* ln1w = (const float*)d_in[5];
  const float* ln1b = (const float*)d_in[6];
  const float* Wq   = (const float*)d_in[7];
  const float* bq   = (const float*)d_in[8];
  const float* Wk   = (const float*)d_in[9];
  const float* bk   = (const float*)d_in[10];
  const float* Wv   = (const float*)d_in[11];
  const float* bv   = (const float*)d_in[12];
  const float* Wo   = (const float*)d_in[13];
  const float* bo   = (const float*)d_in[14];
  const float* ln2w = (const float*)d_in[15];
  const float* ln2b = (const float*)d_in[16];
  const float* W1   = (const float*)d_in[17];
  const float* b1   = (const float*)d_in[18];
  const float* W2   = (const float*)d_in[19];
  const float* b2   = (const float*)d_in[20];
  const float* lnfw = (const float*)d_in[21];
  const float* lnfb = (const float*)d_in[22];
  const float* hw   = (const float*)d_in[23];

  // workspace layout (~289 MB total)
  char* p = (char*)d_ws;
  auto alloc = [&](size_t bytes) {
    char* r = p;
    p += (bytes + 255) & ~(size_t)255;
    return r;
  };
  float* x   = (float*)alloc((size_t)ROWS * DM * 4);       // residual stream f32
  u16*   hb  = (u16*)  alloc((size_t)ROWS * DM * 2);       // LN output bf16
  u16*   qb_ = (u16*)  alloc((size_t)ROWS * DM * 2);
  u16*   kb_ = (u16*)  alloc((size_t)ROWS * DM * 2);
  u16*   vb_ = (u16*)  alloc((size_t)ROWS * DM * 2);
  u16*   yb  = (u16*)  alloc((size_t)ROWS * DM * 2);       // attn out bf16
  u16*   gb  = (u16*)  alloc((size_t)ROWS * 2 * DM * 2);   // MLP hidden bf16
  u16*   Wqb = (u16*)  alloc((size_t)NLAYER * DM * DM * 2);
  u16*   Wkb = (u16*)  alloc((size_t)NLAYER * DM * DM * 2);
  u16*   Wvb = (u16*)  alloc((size_t)NLAYER * DM * DM * 2);
  u16*   Wob = (u16*)  alloc((size_t)NLAYER * DM * DM * 2);
  u16*   W1b = (u16*)  alloc((size_t)NLAYER * 2 * DM * DM * 2);
  u16*   W2b = (u16*)  alloc((size_t)NLAYER * 2 * DM * DM * 2);
  u16*   hwb = (u16*)  alloc((size_t)NVOCAB * DM * 2);

  auto cvt = [&](const float* s, u16* d, size_t n) {
    int n4 = (int)(n / 4);
    k_cvt<<<(n4 + 255) / 256, 256, 0, stream>>>(s, d, n4);
  };
  cvt(Wq, Wqb, (size_t)NLAYER * DM * DM);
  cvt(Wk, Wkb, (size_t)NLAYER * DM * DM);
  cvt(Wv, Wvb, (size_t)NLAYER * DM * DM);
  cvt(Wo, Wob, (size_t)NLAYER * DM * DM);
  cvt(W1, W1b, (size_t)NLAYER * 2 * DM * DM);
  cvt(W2, W2b, (size_t)NLAYER * 2 * DM * DM);
  cvt(hw, hwb, (size_t)NVOCAB * DM);

  k_embed<<<ROWS, 256, 0, stream>>>(idx, ts, tok, gpe, pe, x);

  for (int layer = 0; layer < NLAYER; ++layer) {
    size_t wO  = (size_t)layer * DM * DM;
    size_t w1O = (size_t)layer * 2 * DM * DM;
    size_t dO  = (size_t)layer * DM;
    size_t d2O = (size_t)layer * 2 * DM;
    k_ln<<<ROWS / 4, 256, 0, stream>>>(x, ln1w + dO, ln1b + dO, hb);
    k_gemm<0><<<dim3(64, 8), 256, 0, stream>>>(hb, Wqb + wO, bq + dO, nullptr, qb_, ROWS, DM, DM);
    k_gemm<0><<<dim3(64, 8), 256, 0, stream>>>(hb, Wkb + wO, bk + dO, nullptr, kb_, ROWS, DM, DM);
    k_gemm<0><<<dim3(64, 8), 256, 0, stream>>>(hb, Wvb + wO, bv + dO, nullptr, vb_, ROWS, DM, DM);
    k_attn<<<dim3(SEQ / 64, NHEAD, NB), 256, 0, stream>>>(qb_, kb_, vb_, yb);
    k_gemm<2><<<dim3(64, 8), 256, 0, stream>>>(yb, Wob + wO, bo + dO, x, x, ROWS, DM, DM);
    k_ln<<<ROWS / 4, 256, 0, stream>>>(x, ln2w + dO, ln2b + dO, hb);
    k_gemm<1><<<dim3(64, 16), 256, 0, stream>>>(hb, W1b + w1O, b1 + d2O, nullptr, gb, ROWS, 2 * DM, DM);
    k_gemm<2><<<dim3(64, 8), 256, 0, stream>>>(gb, W2b + w1O, b2 + dO, x, x, ROWS, DM, 2 * DM);
  }
  k_ln<<<ROWS / 4, 256, 0, stream>>>(x, lnfw, lnfb, hb);
  k_gemm<3><<<dim3(64, 64), 256, 0, stream>>>(hb, hwb, nullptr, nullptr, d_out, ROWS, NVOCAB, DM);
}